// Round 1
// baseline (600.088 us; speedup 1.0000x reference)
//
#include <hip/hip_runtime.h>
#include <hip/hip_bf16.h>
#include <math.h>

#define N_NODES 25000
#define N_EDGES 400000

typedef __attribute__((ext_vector_type(8))) __bf16 bf16x8;
typedef __attribute__((ext_vector_type(4))) float f32x4;

__device__ __forceinline__ unsigned short bfbits(float f) {
    __bf16 h = (__bf16)f;
    return __builtin_bit_cast(unsigned short, h);
}

__device__ __forceinline__ float ssp_f(float x) {
    // softplus(x) - log(2)
    float sp = (x > 15.f) ? x : __logf(1.f + __expf(x));
    return sp - 0.69314718056f;
}

// ---------------------------------------------------------------------------
// out[M x 256] = op(A[M x 256] @ B[256 x 256] (+ bias))
// EPI: 0 = none, 1 = ssp(v + bias), 2 = v + bias
// Each block: 64 rows x 128 cols (blockIdx&1 selects col half).
// LDS: B^T half [128 cols][256 k] bf16, XOR-swizzled, 64KB -> 2 blocks/CU.
// ---------------------------------------------------------------------------
template<int EPI>
__global__ __launch_bounds__(256, 2)
void node_gemm(const float* __restrict__ A, const float* __restrict__ B,
               const float* __restrict__ bias, float* __restrict__ out, int M)
{
    extern __shared__ char lds[];
    const int tid  = threadIdx.x;
    const int half = blockIdx.x & 1;
    const int jblk = half << 7;
    const int row0 = (blockIdx.x >> 1) << 6;

    // stage B^T (bf16, swizzle byte^((j&7)<<4)), packed b32 writes
    {
        const int j   = tid & 127;
        const int k2b = (tid >> 7) << 6;
        for (int i = 0; i < 64; ++i) {
            const int k = (k2b + i) * 2;
            const float b0 = B[k * 256 + jblk + j];
            const float b1 = B[(k + 1) * 256 + jblk + j];
            const unsigned pack = (unsigned)bfbits(b0) | ((unsigned)bfbits(b1) << 16);
            *(unsigned*)(lds + ((j * 512 + k * 2) ^ ((j & 7) << 4))) = pack;
        }
    }
    __syncthreads();

    const int wave = tid >> 6;
    const int l    = tid & 63;
    const int lrow = l & 15;
    const int kg   = (l >> 4) << 3;

    f32x4 acc[4][2];
    const f32x4 z4 = {0.f, 0.f, 0.f, 0.f};
    #pragma unroll
    for (int m = 0; m < 4; ++m)
        #pragma unroll
        for (int n = 0; n < 2; ++n) acc[m][n] = z4;

    #pragma unroll
    for (int ks = 0; ks < 8; ++ks) {
        const int k0 = ks * 32 + kg;
        bf16x8 bf[2];
        #pragma unroll
        for (int n = 0; n < 2; ++n) {
            const int jl = (wave << 5) + (n << 4) + lrow;
            bf[n] = *(const bf16x8*)(lds + ((jl * 512 + k0 * 2) ^ ((jl & 7) << 4)));
        }
        #pragma unroll
        for (int m = 0; m < 4; ++m) {
            const int row = row0 + (m << 4) + lrow;
            bf16x8 af;
            if (row < M) {
                const float* ap = A + row * 256 + k0;
                const f32x4 a0 = *(const f32x4*)(ap);
                const f32x4 a1 = *(const f32x4*)(ap + 4);
                #pragma unroll
                for (int b = 0; b < 4; ++b) { af[b] = (__bf16)a0[b]; af[b + 4] = (__bf16)a1[b]; }
            } else {
                #pragma unroll
                for (int b = 0; b < 8; ++b) af[b] = (__bf16)0.f;
            }
            #pragma unroll
            for (int n = 0; n < 2; ++n)
                acc[m][n] = __builtin_amdgcn_mfma_f32_16x16x32_bf16(af, bf[n], acc[m][n], 0, 0, 0);
        }
    }

    #pragma unroll
    for (int m = 0; m < 4; ++m) {
        #pragma unroll
        for (int n = 0; n < 2; ++n) {
            const int j = jblk + (wave << 5) + (n << 4) + lrow;
            float bv = 0.f;
            if (EPI) bv = bias[j];
            #pragma unroll
            for (int r = 0; r < 4; ++r) {
                const int row = row0 + (m << 4) + ((l >> 4) << 2) + r;
                if (row < M) {
                    float v = acc[m][n][r] + bv;
                    if (EPI == 1) v = ssp_f(v);
                    out[row * 256 + j] = v;
                }
            }
        }
    }
}

// ---------------------------------------------------------------------------
// Fused edge kernel: gaussians -> MLP (MFMA) -> cutoff -> gather x[row] ->
// atomic scatter-add into agg[col].
// Block = 256 threads (4 waves), tile = 32 edges, block owns 128 output cols.
// LDS: W2^T half (64KB, swizzled) + t[32][256] bf16 (16KB, swizzled) = 80KB.
// ---------------------------------------------------------------------------
__global__ __launch_bounds__(256, 2)
void edge_kernel(const float* __restrict__ pos, const int* __restrict__ ei,
                 const float* __restrict__ w1, const float* __restrict__ b1,
                 const float* __restrict__ w2, const float* __restrict__ b2,
                 const float* __restrict__ x, float* __restrict__ agg)
{
    extern __shared__ char lds[];
    char* w2t = lds;
    char* tb  = lds + 65536;

    const int tid     = threadIdx.x;
    const int wave    = tid >> 6;
    const int l       = tid & 63;
    const int lrow    = l & 15;
    const int kg      = (l >> 4) << 3;
    const int half    = blockIdx.x & 1;
    const int jblk    = half << 7;
    const int group   = blockIdx.x >> 1;
    const int ngroups = gridDim.x >> 1;

    // stage W2^T half
    {
        const int j   = tid & 127;
        const int k2b = (tid >> 7) << 6;
        for (int i = 0; i < 64; ++i) {
            const int k = (k2b + i) * 2;
            const float v0 = w2[k * 256 + jblk + j];
            const float v1 = w2[(k + 1) * 256 + jblk + j];
            const unsigned pack = (unsigned)bfbits(v0) | ((unsigned)bfbits(v1) << 16);
            *(unsigned*)(w2t + ((j * 512 + k * 2) ^ ((j & 7) << 4))) = pack;
        }
    }

    // W1 B-fragments in registers: wave owns filter cols [wave*64, wave*64+64)
    const float dlt   = 10.f / 49.f;
    const float coeff = -0.5f / (dlt * dlt);
    bf16x8 w1f[4][2];
    #pragma unroll
    for (int n = 0; n < 4; ++n)
        #pragma unroll
        for (int ks = 0; ks < 2; ++ks) {
            bf16x8 v;
            #pragma unroll
            for (int b = 0; b < 8; ++b) {
                const int k = ks * 32 + kg + b;
                const int j = (wave << 6) + (n << 4) + lrow;
                v[b] = (k < 50) ? (__bf16)w1[k * 256 + j] : (__bf16)0.f;
            }
            w1f[n][ks] = v;
        }
    float b1v[4], b2v[2];
    #pragma unroll
    for (int n = 0; n < 4; ++n) b1v[n] = b1[(wave << 6) + (n << 4) + lrow];
    #pragma unroll
    for (int n = 0; n < 2; ++n) b2v[n] = b2[jblk + (wave << 5) + (n << 4) + lrow];

    __syncthreads();

    const f32x4 z4 = {0.f, 0.f, 0.f, 0.f};
    const int NT = N_EDGES / 32;   // 12500, exact
    for (int t = group; t < NT; t += ngroups) {
        const int e0 = t << 5;
        // lanes 0..31 own edge e0+lane (lanes 32..63 duplicate)
        const int el = e0 + (l & 31);
        const int r = ei[el];
        const int c = ei[N_EDGES + el];
        const float dx = pos[r * 3 + 0] - pos[c * 3 + 0];
        const float dy = pos[r * 3 + 1] - pos[c * 3 + 1];
        const float dz = pos[r * 3 + 2] - pos[c * 3 + 2];
        const float d = __fsqrt_rn(dx * dx + dy * dy + dz * dz);

        // ---- GEMM1: gaussians (A, in-register) @ W1 -> acc1 ----
        bf16x8 af[2][2];
        #pragma unroll
        for (int m = 0; m < 2; ++m) {
            const float dm = __shfl(d, (m << 4) + lrow, 64);
            #pragma unroll
            for (int ks = 0; ks < 2; ++ks) {
                bf16x8 v;
                #pragma unroll
                for (int b = 0; b < 8; ++b) {
                    const int k = ks * 32 + kg + b;
                    float g = 0.f;
                    if (k < 50) { const float u = dm - (float)k * dlt; g = __expf(coeff * u * u); }
                    v[b] = (__bf16)g;
                }
                af[m][ks] = v;
            }
        }
        f32x4 acc1[2][4];
        #pragma unroll
        for (int m = 0; m < 2; ++m)
            #pragma unroll
            for (int n = 0; n < 4; ++n) acc1[m][n] = z4;
        #pragma unroll
        for (int ks = 0; ks < 2; ++ks)
            #pragma unroll
            for (int m = 0; m < 2; ++m)
                #pragma unroll
                for (int n = 0; n < 4; ++n)
                    acc1[m][n] = __builtin_amdgcn_mfma_f32_16x16x32_bf16(af[m][ks], w1f[n][ks], acc1[m][n], 0, 0, 0);

        __syncthreads();   // previous tile's GEMM2 reads of tb are done
        // epilogue1: t = ssp(acc1 + b1), bf16 into swizzled LDS
        #pragma unroll
        for (int m = 0; m < 2; ++m)
            #pragma unroll
            for (int n = 0; n < 4; ++n)
                #pragma unroll
                for (int r4 = 0; r4 < 4; ++r4) {
                    const int e = (m << 4) + ((l >> 4) << 2) + r4;
                    const int j = (wave << 6) + (n << 4) + lrow;
                    const float v = ssp_f(acc1[m][n][r4] + b1v[n]);
                    *(__bf16*)(tb + ((e * 512 + j * 2) ^ ((e & 7) << 4))) = (__bf16)v;
                }
        __syncthreads();

        // ---- GEMM2: t[32][256] @ W2[:, jblk:jblk+128] -> acc2 ----
        f32x4 acc2[2][2];
        #pragma unroll
        for (int m = 0; m < 2; ++m)
            #pragma unroll
            for (int n = 0; n < 2; ++n) acc2[m][n] = z4;
        #pragma unroll
        for (int ks = 0; ks < 8; ++ks) {
            const int k0 = ks * 32 + kg;
            bf16x8 bf[2];
            #pragma unroll
            for (int n = 0; n < 2; ++n) {
                const int jl = (wave << 5) + (n << 4) + lrow;
                bf[n] = *(const bf16x8*)(w2t + ((jl * 512 + k0 * 2) ^ ((jl & 7) << 4)));
            }
            #pragma unroll
            for (int m = 0; m < 2; ++m) {
                const int e = (m << 4) + lrow;
                const bf16x8 a = *(const bf16x8*)(tb + ((e * 512 + k0 * 2) ^ ((e & 7) << 4)));
                #pragma unroll
                for (int n = 0; n < 2; ++n)
                    acc2[m][n] = __builtin_amdgcn_mfma_f32_16x16x32_bf16(a, bf[n], acc2[m][n], 0, 0, 0);
            }
        }

        // ---- epilogue2: cutoff * (acc2+b2), gather x[row], scatter agg[col]
        #pragma unroll
        for (int m = 0; m < 2; ++m) {
            #pragma unroll
            for (int r4 = 0; r4 < 4; ++r4) {
                const int e  = (m << 4) + ((l >> 4) << 2) + r4;
                const float de = __shfl(d, e, 64);
                const int re = __shfl(r, e, 64);
                const int ce = __shfl(c, e, 64);
                const float C = 0.5f * (__cosf(de * 0.31415926535f) + 1.f);
                #pragma unroll
                for (int n = 0; n < 2; ++n) {
                    const int j = jblk + (wave << 5) + (n << 4) + lrow;
                    const float W = (acc2[m][n][r4] + b2v[n]) * C;
                    const float msg = x[re * 256 + j] * W;
                    atomicAdd(&agg[ce * 256 + j], msg);
                }
            }
        }
    }
}

__global__ void copy_pos_kernel(const float* __restrict__ p, float* __restrict__ o, int n)
{
    const int i = blockIdx.x * 256 + threadIdx.x;
    if (i < n) o[i] = p[i];
}

extern "C" void kernel_launch(void* const* d_in, const int* in_sizes, int n_in,
                              void* d_out, int out_size, void* d_ws, size_t ws_size,
                              hipStream_t stream)
{
    const float* h      = (const float*)d_in[0];
    const float* pos    = (const float*)d_in[1];
    const float* lin1_w = (const float*)d_in[2];
    const float* lin2_w = (const float*)d_in[3];
    const float* lin2_b = (const float*)d_in[4];
    const float* mlp_w1 = (const float*)d_in[5];
    const float* mlp_b1 = (const float*)d_in[6];
    const float* mlp_w2 = (const float*)d_in[7];
    const float* mlp_b2 = (const float*)d_in[8];
    const float* lin_w  = (const float*)d_in[9];
    const float* lin_b  = (const float*)d_in[10];
    const int*   ei     = (const int*)d_in[11];
    float* out = (float*)d_out;

    float* x   = (float*)d_ws;            // [25000][256] f32
    float* agg = x + N_NODES * 256;       // [25000][256] f32

    // allow >64KB dynamic LDS (ignore errors; idempotent)
    (void)hipFuncSetAttribute((const void*)edge_kernel,
                              hipFuncAttributeMaxDynamicSharedMemorySize, 81920);
    (void)hipFuncSetAttribute((const void*)node_gemm<0>,
                              hipFuncAttributeMaxDynamicSharedMemorySize, 65536);
    (void)hipFuncSetAttribute((const void*)node_gemm<1>,
                              hipFuncAttributeMaxDynamicSharedMemorySize, 65536);
    (void)hipFuncSetAttribute((const void*)node_gemm<2>,
                              hipFuncAttributeMaxDynamicSharedMemorySize, 65536);

    hipMemsetAsync(agg, 0, (size_t)N_NODES * 256 * sizeof(float), stream);

    const dim3 blk(256);
    const int mt = (N_NODES + 63) / 64;   // 391 row-tiles

    // x = h @ lin1_w
    node_gemm<0><<<dim3(mt * 2), blk, 65536, stream>>>(h, lin1_w, nullptr, x, N_NODES);
    // fused edge pipeline -> agg
    edge_kernel<<<dim3(512), blk, 81920, stream>>>(pos, ei, mlp_w1, mlp_b1,
                                                   mlp_w2, mlp_b2, x, agg);
    // x2 = ssp(agg @ lin2_w + lin2_b)   (reuse x buffer)
    node_gemm<1><<<dim3(mt * 2), blk, 65536, stream>>>(agg, lin2_w, lin2_b, x, N_NODES);
    // h_update = x2 @ lin_w + lin_b
    node_gemm<2><<<dim3(mt * 2), blk, 65536, stream>>>(x, lin_w, lin_b, out, N_NODES);
    // pos passthrough
    copy_pos_kernel<<<dim3((N_NODES * 3 + 255) / 256), blk, 0, stream>>>(pos, out + N_NODES * 256, N_NODES * 3);
}

// Round 2
// 556.225 us; speedup vs baseline: 1.0789x; 1.0789x over previous
//
#include <hip/hip_runtime.h>
#include <hip/hip_bf16.h>
#include <math.h>

#define N_NODES 25000
#define N_EDGES 400000
#define NTILES (N_EDGES / 32)   // 12500 exact

typedef __attribute__((ext_vector_type(8))) __bf16 bf16x8;
typedef __attribute__((ext_vector_type(4))) float f32x4;
typedef __attribute__((ext_vector_type(2))) unsigned uint32x2;

__device__ __forceinline__ unsigned short bfbits(float f) {
    __bf16 h = (__bf16)f;
    return __builtin_bit_cast(unsigned short, h);
}

__device__ __forceinline__ float ssp_f(float x) {
    // softplus(x) - log(2)
    float sp = (x > 15.f) ? x : __logf(1.f + __expf(x));
    return sp - 0.69314718056f;
}

// ---------------------------------------------------------------------------
// out[M x 256] = op(A[M x 256] @ B[256 x 256] (+ bias))
// EPI: 0 = none, 1 = ssp(v + bias), 2 = v + bias   (unchanged from R1)
// ---------------------------------------------------------------------------
template<int EPI>
__global__ __launch_bounds__(256, 2)
void node_gemm(const float* __restrict__ A, const float* __restrict__ B,
               const float* __restrict__ bias, float* __restrict__ out, int M)
{
    extern __shared__ char lds[];
    const int tid  = threadIdx.x;
    const int half = blockIdx.x & 1;
    const int jblk = half << 7;
    const int row0 = (blockIdx.x >> 1) << 6;

    {
        const int j   = tid & 127;
        const int k2b = (tid >> 7) << 6;
        for (int i = 0; i < 64; ++i) {
            const int k = (k2b + i) * 2;
            const float b0 = B[k * 256 + jblk + j];
            const float b1 = B[(k + 1) * 256 + jblk + j];
            const unsigned pack = (unsigned)bfbits(b0) | ((unsigned)bfbits(b1) << 16);
            *(unsigned*)(lds + ((j * 512 + k * 2) ^ ((j & 7) << 4))) = pack;
        }
    }
    __syncthreads();

    const int wave = tid >> 6;
    const int l    = tid & 63;
    const int lrow = l & 15;
    const int kg   = (l >> 4) << 3;

    f32x4 acc[4][2];
    const f32x4 z4 = {0.f, 0.f, 0.f, 0.f};
    #pragma unroll
    for (int m = 0; m < 4; ++m)
        #pragma unroll
        for (int n = 0; n < 2; ++n) acc[m][n] = z4;

    #pragma unroll
    for (int ks = 0; ks < 8; ++ks) {
        const int k0 = ks * 32 + kg;
        bf16x8 bf[2];
        #pragma unroll
        for (int n = 0; n < 2; ++n) {
            const int jl = (wave << 5) + (n << 4) + lrow;
            bf[n] = *(const bf16x8*)(lds + ((jl * 512 + k0 * 2) ^ ((jl & 7) << 4)));
        }
        #pragma unroll
        for (int m = 0; m < 4; ++m) {
            const int row = row0 + (m << 4) + lrow;
            bf16x8 af;
            if (row < M) {
                const float* ap = A + row * 256 + k0;
                const f32x4 a0 = *(const f32x4*)(ap);
                const f32x4 a1 = *(const f32x4*)(ap + 4);
                #pragma unroll
                for (int b = 0; b < 4; ++b) { af[b] = (__bf16)a0[b]; af[b + 4] = (__bf16)a1[b]; }
            } else {
                #pragma unroll
                for (int b = 0; b < 8; ++b) af[b] = (__bf16)0.f;
            }
            #pragma unroll
            for (int n = 0; n < 2; ++n)
                acc[m][n] = __builtin_amdgcn_mfma_f32_16x16x32_bf16(af, bf[n], acc[m][n], 0, 0, 0);
        }
    }

    #pragma unroll
    for (int m = 0; m < 4; ++m) {
        #pragma unroll
        for (int n = 0; n < 2; ++n) {
            const int j = jblk + (wave << 5) + (n << 4) + lrow;
            float bv = 0.f;
            if (EPI) bv = bias[j];
            #pragma unroll
            for (int r = 0; r < 4; ++r) {
                const int row = row0 + (m << 4) + ((l >> 4) << 2) + r;
                if (row < M) {
                    float v = acc[m][n][r] + bv;
                    if (EPI == 1) v = ssp_f(v);
                    out[row * 256 + j] = v;
                }
            }
        }
    }
}

// ---------------------------------------------------------------------------
// Counting sort of edges by target col: hist -> scan -> scatter(perm)
// ---------------------------------------------------------------------------
__global__ void hist_kernel(const int* __restrict__ ei, int* __restrict__ hist)
{
    const int i = blockIdx.x * 256 + threadIdx.x;
    if (i < N_EDGES) atomicAdd(&hist[ei[N_EDGES + i]], 1);
}

__global__ void scan_kernel(int* __restrict__ hist)
{
    __shared__ int part[256];
    const int t  = threadIdx.x;
    const int CH = (N_NODES + 255) / 256;   // 98
    const int lo = t * CH;
    const int hi = (lo + CH < N_NODES) ? lo + CH : N_NODES;
    int s = 0;
    for (int i = lo; i < hi; ++i) s += hist[i];
    part[t] = s;
    __syncthreads();
    for (int off = 1; off < 256; off <<= 1) {
        const int v = part[t];
        const int u = (t >= off) ? part[t - off] : 0;
        __syncthreads();
        part[t] = v + u;
        __syncthreads();
    }
    int base = (t == 0) ? 0 : part[t - 1];
    for (int i = lo; i < hi; ++i) { const int v = hist[i]; hist[i] = base; base += v; }
}

__global__ void scatter_kernel(const int* __restrict__ ei, int* __restrict__ hist,
                               int* __restrict__ perm)
{
    const int i = blockIdx.x * 256 + threadIdx.x;
    if (i < N_EDGES) {
        const int c = ei[N_EDGES + i];
        const int p = atomicAdd(&hist[c], 1);
        perm[p] = i;
    }
}

// ---------------------------------------------------------------------------
// Fused edge kernel over SORTED edges.
// Block = 256 threads, tile = 32 sorted edges, block owns 128 output cols.
// LDS: w2t half 64KB (swizzled) + 16KB union region rb:
//   phase gauss: rb[0:4K)   g[e][64k] bf16   swz ^((e&7)<<4)
//   phase tb:    rb[0:16K)  t[e][256k] bf16  swz ^((e&7)<<4)
//   phase msg:   rb[0:8K)   msg[j][32e] bf16 swz ^((j&7)<<4); cols[32] int at rb+8K
// Epilogue: run-length reduce sorted cols -> few atomics per tile.
// ---------------------------------------------------------------------------
__global__ __launch_bounds__(256, 2)
void edge_kernel(const float* __restrict__ pos, const int* __restrict__ ei,
                 const int* __restrict__ perm,
                 const float* __restrict__ w1, const float* __restrict__ b1,
                 const float* __restrict__ w2, const float* __restrict__ b2,
                 const float* __restrict__ x, float* __restrict__ agg)
{
    extern __shared__ char lds[];
    char* w2t = lds;
    char* rb  = lds + 65536;
    int* colsm = (int*)(rb + 8192);

    const int tid   = threadIdx.x;
    const int wave  = tid >> 6;
    const int l     = tid & 63;
    const int lrow  = l & 15;
    const int g     = l >> 4;
    const int kg    = g << 3;
    const int half  = blockIdx.x & 1;
    const int jblk  = half << 7;
    const int group = blockIdx.x >> 1;

    // stage W2^T half
    {
        const int j   = tid & 127;
        const int k2b = (tid >> 7) << 6;
        for (int i = 0; i < 64; ++i) {
            const int k = (k2b + i) * 2;
            const float v0 = w2[k * 256 + jblk + j];
            const float v1 = w2[(k + 1) * 256 + jblk + j];
            const unsigned pack = (unsigned)bfbits(v0) | ((unsigned)bfbits(v1) << 16);
            *(unsigned*)(w2t + ((j * 512 + k * 2) ^ ((j & 7) << 4))) = pack;
        }
    }

    // W1 B-fragments in registers: wave owns filter cols [wave*64, wave*64+64)
    const float dlt   = 10.f / 49.f;
    const float coeff = -0.5f / (dlt * dlt);
    bf16x8 w1f[4][2];
    #pragma unroll
    for (int n = 0; n < 4; ++n)
        #pragma unroll
        for (int ks = 0; ks < 2; ++ks) {
            bf16x8 v;
            #pragma unroll
            for (int b = 0; b < 8; ++b) {
                const int k = ks * 32 + kg + b;
                const int j = (wave << 6) + (n << 4) + lrow;
                v[b] = (k < 50) ? (__bf16)w1[k * 256 + j] : (__bf16)0.f;
            }
            w1f[n][ks] = v;
        }
    float b1v[4], b2v[2];
    #pragma unroll
    for (int n = 0; n < 4; ++n) b1v[n] = b1[(wave << 6) + (n << 4) + lrow];
    #pragma unroll
    for (int n = 0; n < 2; ++n) b2v[n] = b2[jblk + (wave << 5) + (n << 4) + lrow];

    __syncthreads();   // w2t ready

    const f32x4 z4 = {0.f, 0.f, 0.f, 0.f};
    const int CH = (NTILES + 255) / 256;    // 49 tiles per group, contiguous
    const int t0 = group * CH;
    int t1 = t0 + CH; if (t1 > NTILES) t1 = NTILES;

    const int ge = tid >> 3;          // gaussian producer: edge
    const int gk = (tid & 7) << 3;    // gaussian producer: k-base (8 wide)

    for (int t = t0; t < t1; ++t) {
        const int e0 = t << 5;

        // per-wave edge meta: lanes hold edge e = l&31 (upper 32 duplicate)
        const int es  = e0 + (l & 31);
        const int eid = perm[es];
        const int r   = ei[eid];
        const int c   = ei[N_EDGES + eid];
        {   // only C(d) is needed from here on
        }
        const float dx = pos[r * 3 + 0] - pos[c * 3 + 0];
        const float dy = pos[r * 3 + 1] - pos[c * 3 + 1];
        const float dz = pos[r * 3 + 2] - pos[c * 3 + 2];
        const float d  = __fsqrt_rn(dx * dx + dy * dy + dz * dz);
        const float Cc = 0.5f * (__cosf(d * 0.31415926535f) + 1.f);

        // gaussian producer (one (e, 8k) slab per thread) into registers
        const int geid = perm[e0 + ge];
        const int grn  = ei[geid];
        const int gcn  = ei[N_EDGES + geid];
        const float gx = pos[grn * 3 + 0] - pos[gcn * 3 + 0];
        const float gy = pos[grn * 3 + 1] - pos[gcn * 3 + 1];
        const float gz = pos[grn * 3 + 2] - pos[gcn * 3 + 2];
        const float gd = __fsqrt_rn(gx * gx + gy * gy + gz * gz);
        bf16x8 gv;
        #pragma unroll
        for (int b = 0; b < 8; ++b) {
            const int k = gk + b;
            float gval = 0.f;
            if (k < 50) { const float u = gd - (float)k * dlt; gval = __expf(coeff * u * u); }
            gv[b] = (__bf16)gval;
        }

        __syncthreads();   // B1: previous iteration's readers done with rb
        *(bf16x8*)(rb + ((ge * 128 + (gk << 1)) ^ ((ge & 7) << 4))) = gv;
        __syncthreads();   // B2: gaussians visible

        // ---- GEMM1: gauss[32][64] @ W1 -> acc1 (wave owns 64 filter cols)
        bf16x8 af[2][2];
        #pragma unroll
        for (int m = 0; m < 2; ++m) {
            const int e = (m << 4) + lrow;
            #pragma unroll
            for (int ks = 0; ks < 2; ++ks)
                af[m][ks] = *(const bf16x8*)(rb + ((e * 128 + ((ks << 5) + kg) * 2) ^ ((e & 7) << 4)));
        }
        f32x4 acc1[2][4];
        #pragma unroll
        for (int m = 0; m < 2; ++m)
            #pragma unroll
            for (int n = 0; n < 4; ++n) acc1[m][n] = z4;
        #pragma unroll
        for (int ks = 0; ks < 2; ++ks)
            #pragma unroll
            for (int m = 0; m < 2; ++m)
                #pragma unroll
                for (int n = 0; n < 4; ++n)
                    acc1[m][n] = __builtin_amdgcn_mfma_f32_16x16x32_bf16(af[m][ks], w1f[n][ks], acc1[m][n], 0, 0, 0);
        __syncthreads();   // B3: gauss reads done; tb region writable

        // ---- epilogue1: t = ssp(acc1 + b1) -> tb bf16 (swizzled)
        #pragma unroll
        for (int m = 0; m < 2; ++m)
            #pragma unroll
            for (int n = 0; n < 4; ++n)
                #pragma unroll
                for (int r4 = 0; r4 < 4; ++r4) {
                    const int e = (m << 4) + (g << 2) + r4;
                    const int k = (wave << 6) + (n << 4) + lrow;
                    const float v = ssp_f(acc1[m][n][r4] + b1v[n]);
                    *(__bf16*)(rb + ((e * 512 + k * 2) ^ ((e & 7) << 4))) = (__bf16)v;
                }
        __syncthreads();   // B4: tb ready

        // ---- GEMM2: t[32][256] @ W2[:, jblk:+128] -> acc2
        f32x4 acc2[2][2];
        #pragma unroll
        for (int m = 0; m < 2; ++m)
            #pragma unroll
            for (int n = 0; n < 2; ++n) acc2[m][n] = z4;
        #pragma unroll
        for (int ks = 0; ks < 8; ++ks) {
            const int k0 = (ks << 5) + kg;
            bf16x8 bfr[2];
            #pragma unroll
            for (int n = 0; n < 2; ++n) {
                const int jl = (wave << 5) + (n << 4) + lrow;
                bfr[n] = *(const bf16x8*)(w2t + ((jl * 512 + k0 * 2) ^ ((jl & 7) << 4)));
            }
            #pragma unroll
            for (int m = 0; m < 2; ++m) {
                const int e = (m << 4) + lrow;
                const bf16x8 a = *(const bf16x8*)(rb + ((e * 512 + k0 * 2) ^ ((e & 7) << 4)));
                #pragma unroll
                for (int n = 0; n < 2; ++n)
                    acc2[m][n] = __builtin_amdgcn_mfma_f32_16x16x32_bf16(a, bfr[n], acc2[m][n], 0, 0, 0);
            }
        }
        __syncthreads();   // B5: tb reads done; msg region writable

        // ---- msg epilogue: msg = (acc2+b2)*C(d)*x[row] -> msgb[j][e] bf16
        #pragma unroll
        for (int m = 0; m < 2; ++m) {
            const int base_e = (m << 4) + (g << 2);
            #pragma unroll
            for (int n = 0; n < 2; ++n) {
                const int jloc = (wave << 5) + (n << 4) + lrow;
                float vv[4];
                #pragma unroll
                for (int r4 = 0; r4 < 4; ++r4) {
                    const int e = base_e + r4;
                    const float Ce = __shfl(Cc, e, 64);
                    const int   re = __shfl(r, e, 64);
                    const float xv = x[re * 256 + jblk + jloc];
                    vv[r4] = (acc2[m][n][r4] + b2v[n]) * Ce * xv;
                }
                uint32x2 pk;
                pk[0] = (unsigned)bfbits(vv[0]) | ((unsigned)bfbits(vv[1]) << 16);
                pk[1] = (unsigned)bfbits(vv[2]) | ((unsigned)bfbits(vv[3]) << 16);
                *(uint32x2*)(rb + ((jloc * 64 + base_e * 2) ^ ((jloc & 7) << 4))) = pk;
            }
        }
        if (tid < 32) colsm[tid] = c;   // wave0 lanes 0..31 hold col of edge e=tid
        __syncthreads();   // B6: msg + cols ready

        // ---- reader: 128 threads, one j-column each; run-length reduce
        if (tid < 128) {
            const int j = tid;
            const bf16x8 q0 = *(const bf16x8*)(rb + ((j * 64 +  0) ^ ((j & 7) << 4)));
            const bf16x8 q1 = *(const bf16x8*)(rb + ((j * 64 + 16) ^ ((j & 7) << 4)));
            const bf16x8 q2 = *(const bf16x8*)(rb + ((j * 64 + 32) ^ ((j & 7) << 4)));
            const bf16x8 q3 = *(const bf16x8*)(rb + ((j * 64 + 48) ^ ((j & 7) << 4)));
            float* aj = agg + jblk + j;
            int prev = colsm[0];
            float s = 0.f;
            #pragma unroll
            for (int e = 0; e < 32; ++e) {
                const float v = (e < 8) ? (float)q0[e] :
                                (e < 16) ? (float)q1[e - 8] :
                                (e < 24) ? (float)q2[e - 16] : (float)q3[e - 24];
                const int ce = colsm[e];
                if (ce != prev) {            // wave-uniform (sorted cols)
                    atomicAdd(aj + (size_t)prev * 256, s);
                    s = 0.f; prev = ce;
                }
                s += v;
            }
            atomicAdd(aj + (size_t)prev * 256, s);
        }
    }
}

__global__ void copy_pos_kernel(const float* __restrict__ p, float* __restrict__ o, int n)
{
    const int i = blockIdx.x * 256 + threadIdx.x;
    if (i < n) o[i] = p[i];
}

extern "C" void kernel_launch(void* const* d_in, const int* in_sizes, int n_in,
                              void* d_out, int out_size, void* d_ws, size_t ws_size,
                              hipStream_t stream)
{
    const float* h      = (const float*)d_in[0];
    const float* pos    = (const float*)d_in[1];
    const float* lin1_w = (const float*)d_in[2];
    const float* lin2_w = (const float*)d_in[3];
    const float* lin2_b = (const float*)d_in[4];
    const float* mlp_w1 = (const float*)d_in[5];
    const float* mlp_b1 = (const float*)d_in[6];
    const float* mlp_w2 = (const float*)d_in[7];
    const float* mlp_b2 = (const float*)d_in[8];
    const float* lin_w  = (const float*)d_in[9];
    const float* lin_b  = (const float*)d_in[10];
    const int*   ei     = (const int*)d_in[11];
    float* out = (float*)d_out;

    float* x    = (float*)d_ws;                         // [25000][256] f32
    float* agg  = x + (size_t)N_NODES * 256;            // [25000][256] f32
    int*   hist = (int*)(agg + (size_t)N_NODES * 256);  // [25000] int
    int*   perm = hist + N_NODES;                       // [400000] int

    (void)hipFuncSetAttribute((const void*)edge_kernel,
                              hipFuncAttributeMaxDynamicSharedMemorySize, 81920);
    (void)hipFuncSetAttribute((const void*)node_gemm<0>,
                              hipFuncAttributeMaxDynamicSharedMemorySize, 65536);
    (void)hipFuncSetAttribute((const void*)node_gemm<1>,
                              hipFuncAttributeMaxDynamicSharedMemorySize, 65536);
    (void)hipFuncSetAttribute((const void*)node_gemm<2>,
                              hipFuncAttributeMaxDynamicSharedMemorySize, 65536);

    hipMemsetAsync(agg, 0, (size_t)N_NODES * 256 * sizeof(float), stream);
    hipMemsetAsync(hist, 0, (size_t)N_NODES * sizeof(int), stream);

    const dim3 blk(256);
    const int mt = (N_NODES + 63) / 64;   // 391 row-tiles
    const int eb = (N_EDGES + 255) / 256; // 1563 blocks

    // x = h @ lin1_w  (independent of the sort)
    node_gemm<0><<<dim3(mt * 2), blk, 65536, stream>>>(h, lin1_w, nullptr, x, N_NODES);

    // counting sort of edges by col
    hist_kernel<<<dim3(eb), blk, 0, stream>>>(ei, hist);
    scan_kernel<<<dim3(1), blk, 0, stream>>>(hist);
    scatter_kernel<<<dim3(eb), blk, 0, stream>>>(ei, hist, perm);

    // fused edge pipeline -> agg
    edge_kernel<<<dim3(512), blk, 81920, stream>>>(pos, ei, perm, mlp_w1, mlp_b1,
                                                   mlp_w2, mlp_b2, x, agg);

    // x2 = ssp(agg @ lin2_w + lin2_b)   (reuse x buffer)
    node_gemm<1><<<dim3(mt * 2), blk, 65536, stream>>>(agg, lin2_w, lin2_b, x, N_NODES);
    // h_update = x2 @ lin_w + lin_b
    node_gemm<2><<<dim3(mt * 2), blk, 65536, stream>>>(x, lin_w, lin_b, out, N_NODES);
    // pos passthrough
    copy_pos_kernel<<<dim3((N_NODES * 3 + 255) / 256), blk, 0, stream>>>(pos, out + N_NODES * 256, N_NODES * 3);
}